// Round 4
// baseline (15.267 us; speedup 1.0000x reference)
//
#include <hip/hip_runtime.h>

// TripletHardLoss, barrier-free tile kernel + tiny reduce kernel.
// loss = mean over 513*512 terms of relu(d_ap[i] - d_an + 1), where d_an runs
// over ||a_i - b_j + eps|| (j != i), ||a_i - c_i + eps||, ||a_i - d_i + eps||.
// With a' = a + eps:  ||a'_i - b_j||^2 = na[i] + nb[j] - 2 (a'_i . b_j).
// Gram via bf16 MFMA (direct-from-global fragments); norms/diagonals in fp32
// computed from the SAME loads inside the kc loop; cross-lane distribution via
// shuffles only — no LDS staging, no barriers until the 4-float block reduce.

#define EPSV 1e-6f
#define MARGINV 1.0f

typedef float  v4f  __attribute__((ext_vector_type(4)));
typedef short  s8v  __attribute__((ext_vector_type(8)));

constexpr int BB = 512;
constexpr int DD = 256;
constexpr int D4 = DD / 4;        // 64 float4 per row
constexpr int TT = 32;            // 32x32 tile per block
constexpr int NB = BB / TT;       // 16
constexpr int NBLK = NB * NB;     // 256
constexpr float INV_N = 1.0f / (513.0f * 512.0f);

__device__ __forceinline__ unsigned short f2bf(float f) {
    unsigned int u = __float_as_uint(f);
    unsigned int r = (u + 0x7FFFu + ((u >> 16) & 1u)) >> 16;   // RNE
    return (unsigned short)r;
}

__device__ __forceinline__ unsigned int pk(float x, float y) {
    return (unsigned int)f2bf(x) | ((unsigned int)f2bf(y) << 16);
}

__global__ void __launch_bounds__(256) triplet_tile_kernel(
    const float* __restrict__ a, const float* __restrict__ b,
    const float* __restrict__ c, const float* __restrict__ d,
    float* __restrict__ partial)
{
    __shared__ float sRed[4];

    const int t    = threadIdx.x;
    const int l    = t & 63;
    const int w    = t >> 6;        // wave 0..3
    const int wi   = w >> 1;        // i half
    const int wj   = w & 1;         // j half
    const int bi   = blockIdx.x >> 4;
    const int bj   = blockIdx.x & (NB - 1);
    const int i0   = bi * TT;
    const int j0   = bj * TT;
    const int r16  = l & 15;        // row-class within 16
    const int kseg = l >> 4;        // 0..3 (k-segment of 8)

    const int arow = i0 + wi * 16 + r16;   // global a-row (also b-diag row)
    const int brow = j0 + wj * 16 + r16;   // global b-col row

    const float4* a4 = (const float4*)a;
    const float4* b4 = (const float4*)b;

    // c-terms owned by bj==1 (wj==0 waves), d-terms by bj==2 (wj==0 waves)
    const bool doe = (wj == 0) && (bj == 1 || bj == 2);
    const float4* e4 = (const float4*)((bj == 1) ? c : d);

    float na = 0.f, nb = 0.f, dap = 0.f, dae = 0.f;
    v4f acc = {0.f, 0.f, 0.f, 0.f};

    #pragma unroll
    for (int kc = 0; kc < 8; ++kc) {
        const int k4 = kc * 8 + kseg * 2;     // float4 column index

        float4 av0 = a4[arow * D4 + k4];
        float4 av1 = a4[arow * D4 + k4 + 1];
        av0.x += EPSV; av0.y += EPSV; av0.z += EPSV; av0.w += EPSV;
        av1.x += EPSV; av1.y += EPSV; av1.z += EPSV; av1.w += EPSV;

        float4 bv0 = b4[brow * D4 + k4];
        float4 bv1 = b4[brow * D4 + k4 + 1];
        float4 bd0 = b4[arow * D4 + k4];
        float4 bd1 = b4[arow * D4 + k4 + 1];

        na += av0.x*av0.x + av0.y*av0.y + av0.z*av0.z + av0.w*av0.w
            + av1.x*av1.x + av1.y*av1.y + av1.z*av1.z + av1.w*av1.w;
        nb += bv0.x*bv0.x + bv0.y*bv0.y + bv0.z*bv0.z + bv0.w*bv0.w
            + bv1.x*bv1.x + bv1.y*bv1.y + bv1.z*bv1.z + bv1.w*bv1.w;

        float e0 = av0.x - bd0.x, e1 = av0.y - bd0.y;
        float e2 = av0.z - bd0.z, e3 = av0.w - bd0.w;
        float e4_ = av1.x - bd1.x, e5 = av1.y - bd1.y;
        float e6 = av1.z - bd1.z, e7 = av1.w - bd1.w;
        dap += e0*e0 + e1*e1 + e2*e2 + e3*e3 + e4_*e4_ + e5*e5 + e6*e6 + e7*e7;

        if (doe) {
            float4 cv0 = e4[arow * D4 + k4];
            float4 cv1 = e4[arow * D4 + k4 + 1];
            float f0 = av0.x - cv0.x, f1 = av0.y - cv0.y;
            float f2 = av0.z - cv0.z, f3 = av0.w - cv0.w;
            float f4_ = av1.x - cv1.x, f5 = av1.y - cv1.y;
            float f6 = av1.z - cv1.z, f7 = av1.w - cv1.w;
            dae += f0*f0 + f1*f1 + f2*f2 + f3*f3 + f4_*f4_ + f5*f5 + f6*f6 + f7*f7;
        }

        union { s8v v; unsigned int u[4]; } AF, BF;
        AF.u[0] = pk(av0.x, av0.y); AF.u[1] = pk(av0.z, av0.w);
        AF.u[2] = pk(av1.x, av1.y); AF.u[3] = pk(av1.z, av1.w);
        BF.u[0] = pk(bv0.x, bv0.y); BF.u[1] = pk(bv0.z, bv0.w);
        BF.u[2] = pk(bv1.x, bv1.y); BF.u[3] = pk(bv1.z, bv1.w);
        acc = __builtin_amdgcn_mfma_f32_16x16x32_bf16(AF.v, BF.v, acc, 0, 0, 0);
    }

    // ---- fold stride-16 lane groups: each class (l&15) now holds full sums
    na  += __shfl_xor(na, 16);  na  += __shfl_xor(na, 32);
    nb  += __shfl_xor(nb, 16);  nb  += __shfl_xor(nb, 32);
    dap += __shfl_xor(dap, 16); dap += __shfl_xor(dap, 32);
    dap = sqrtf(dap);
    if (doe) {
        dae += __shfl_xor(dae, 16); dae += __shfl_xor(dae, 32);
        dae = sqrtf(dae);
    }

    // ---- epilogue: C/D layout col = l&15, row = (l>>4)*4 + r --------------
    float s = 0.f;
    const float nbj = nb;                 // col = l&15: already lane-local
    const int jg = j0 + wj * 16 + r16;
    #pragma unroll
    for (int r = 0; r < 4; ++r) {
        const int src = kseg * 4 + r;     // lane class holding this row
        float nai  = __shfl(na,  src);
        float dapi = __shfl(dap, src);
        const int il = wi * 16 + src;
        const int ig = i0 + il;
        float D2 = nai + nbj - 2.0f * acc[r];
        float dist = sqrtf(fmaxf(D2, 0.f));
        if (ig != jg) s += fmaxf(dapi - dist + MARGINV, 0.f);
    }
    if (doe && l < 16) {
        // lane l holds dap/dae for global row i0 + wi*16 + l
        s += fmaxf(dap - dae + MARGINV, 0.f);
    }

    // ---- deterministic block reduction -> one partial ----------------------
    #pragma unroll
    for (int off = 32; off; off >>= 1) s += __shfl_down(s, off);
    if (l == 0) sRed[w] = s;
    __syncthreads();
    if (t == 0) partial[blockIdx.x] = ((sRed[0] + sRed[1]) + sRed[2]) + sRed[3];
}

// ---------------------------------------------------------------------------
// Final deterministic fixed-order sum of the 256 partials.
__global__ void __launch_bounds__(64) triplet_reduce_kernel(
    const float* __restrict__ partial, float* __restrict__ out)
{
    int t = threadIdx.x;
    float x0 = partial[t];
    float x1 = partial[t + 64];
    float x2 = partial[t + 128];
    float x3 = partial[t + 192];
    float x = ((x0 + x1) + x2) + x3;
    #pragma unroll
    for (int off = 32; off; off >>= 1) x += __shfl_down(x, off);
    if (t == 0) out[0] = x * INV_N;
}

extern "C" void kernel_launch(void* const* d_in, const int* in_sizes, int n_in,
                              void* d_out, int out_size, void* d_ws, size_t ws_size,
                              hipStream_t stream) {
    const float* a = (const float*)d_in[0];
    const float* b = (const float*)d_in[1];
    const float* c = (const float*)d_in[2];
    const float* d = (const float*)d_in[3];
    float* partial = (float*)d_ws;               // 256 floats

    triplet_tile_kernel<<<NBLK, 256, 0, stream>>>(a, b, c, d, partial);
    triplet_reduce_kernel<<<1, 64, 0, stream>>>(partial, (float*)d_out);
}

// Round 5
// 13.258 us; speedup vs baseline: 1.1516x; 1.1516x over previous
//
#include <hip/hip_runtime.h>

// TripletHardLoss. Round-3 structure (coalesced stage -> LDS -> MFMA) with:
//  - norms/diagonals folded into the staging loads (no second global pass)
//  - 512-thread blocks, 8 waves: MFMA K-split in half, combined via LDS
//  - c-diag owned by bj==1 blocks, d-diag by bj==2 (straggler balance)
//  - bijective XCD-chunk swizzle for L2 locality
// Math: a' = a + eps;  ||a'_i - b_j||^2 = na[i] + nb[j] - 2 (a'_i . b_j).
// Gram via bf16 MFMA (verified absmax 0 vs threshold 2.3e-2); norms and all
// diagonal distances in exact fp32.

#define EPSV 1e-6f
#define MARGINV 1.0f

typedef float  v4f  __attribute__((ext_vector_type(4)));
typedef short  s8v  __attribute__((ext_vector_type(8)));

constexpr int BB = 512;
constexpr int DD = 256;
constexpr int D4 = DD / 4;        // 64 float4 per row
constexpr int TT = 32;            // 32x32 tile per block
constexpr int NB = BB / TT;       // 16
constexpr int NBLK = NB * NB;     // 256
constexpr float INV_N = 1.0f / (513.0f * 512.0f);

__device__ __forceinline__ unsigned short f2bf(float f) {
    unsigned int u = __float_as_uint(f);
    unsigned int r = (u + 0x7FFFu + ((u >> 16) & 1u)) >> 16;   // RNE
    return (unsigned short)r;
}
__device__ __forceinline__ unsigned int pk(float x, float y) {
    return (unsigned int)f2bf(x) | ((unsigned int)f2bf(y) << 16);
}
__device__ __forceinline__ float dot4(float4 v) {
    return v.x * v.x + v.y * v.y + v.z * v.z + v.w * v.w;
}

__global__ void __launch_bounds__(512) triplet_tile_kernel(
    const float* __restrict__ a, const float* __restrict__ b,
    const float* __restrict__ c, const float* __restrict__ d,
    float* __restrict__ partial)
{
    __shared__ __align__(16) unsigned short sA[TT * DD];  // bf16 a', swizzled
    __shared__ __align__(16) unsigned short sB[TT * DD];  // bf16 b,  swizzled
    __shared__ v4f   sCmb[4 * 64];                        // K-half combine
    __shared__ float sNa[TT], sNb[TT], sDap[TT], sDae[TT];
    __shared__ float sRed[4];

    const int t = threadIdx.x;
    const int l = t & 63;
    const int w = t >> 6;                  // wave 0..7

    // bijective XCD-chunk swizzle: same XCD -> contiguous tile range
    const int bid = blockIdx.x;
    const int swz = (bid & 7) * 32 + (bid >> 3);
    const int bi = swz >> 4;
    const int bj = swz & (NB - 1);
    const int i0 = bi * TT;
    const int j0 = bj * TT;

    const float4* a4 = (const float4*)a;
    const float4* b4 = (const float4*)b;
    const bool doe = (bj == 1) || (bj == 2);
    const float4* e4 = (const float4*)((bj == 1) ? c : d);

    // ---- fused stage + norms: wave w owns rows {w, w+8, w+16, w+24},
    //      lane = float4 column. Loads fully coalesced (wave = 1KB/row).
    float naP[4], nbP[4], dapP[4], daeP[4];
    #pragma unroll
    for (int kk = 0; kk < 4; ++kk) {
        const int row = w + 8 * kk;
        float4 av = a4[(i0 + row) * D4 + l];
        av.x += EPSV; av.y += EPSV; av.z += EPSV; av.w += EPSV;
        float4 bv = b4[(j0 + row) * D4 + l];
        float4 bd = b4[(i0 + row) * D4 + l];
        naP[kk] = dot4(av);
        nbP[kk] = dot4(bv);
        float4 df;
        df.x = av.x - bd.x; df.y = av.y - bd.y;
        df.z = av.z - bd.z; df.w = av.w - bd.w;
        dapP[kk] = dot4(df);
        if (doe) {
            float4 ev = e4[(i0 + row) * D4 + l];
            float4 ef;
            ef.x = av.x - ev.x; ef.y = av.y - ev.y;
            ef.z = av.z - ev.z; ef.w = av.w - ev.w;
            daeP[kk] = dot4(ef);
        }
        const int sw = (row & 7) << 3;     // ushort-index XOR (16B granule)
        *(uint2*)&sA[(row * DD + l * 4) ^ sw] = make_uint2(pk(av.x, av.y), pk(av.z, av.w));
        *(uint2*)&sB[(row * DD + l * 4) ^ sw] = make_uint2(pk(bv.x, bv.y), pk(bv.z, bv.w));
    }
    // 64-lane reductions -> per-row scalars
    #pragma unroll
    for (int kk = 0; kk < 4; ++kk) {
        float x0 = naP[kk], x1 = nbP[kk], x2 = dapP[kk];
        #pragma unroll
        for (int off = 32; off; off >>= 1) {
            x0 += __shfl_down(x0, off);
            x1 += __shfl_down(x1, off);
            x2 += __shfl_down(x2, off);
        }
        if (l == 0) {
            const int row = w + 8 * kk;
            sNa[row] = x0; sNb[row] = x1; sDap[row] = sqrtf(x2);
        }
        if (doe) {
            float x3 = daeP[kk];
            #pragma unroll
            for (int off = 32; off; off >>= 1) x3 += __shfl_down(x3, off);
            if (l == 0) sDae[w + 8 * kk] = sqrtf(x3);
        }
    }
    __syncthreads();

    // ---- MFMA: 4 subtiles x 2 K-halves across 8 waves ----------------------
    const int sub  = w & 3, half = w >> 2;
    const int wi   = sub >> 1, wj = sub & 1;
    const int arow = wi * 16 + (l & 15);
    const int brow = wj * 16 + (l & 15);
    const int asw  = (arow & 7) << 3;
    const int bsw  = (brow & 7) << 3;
    const int kbase = (l >> 4) * 8;

    v4f acc = {0.f, 0.f, 0.f, 0.f};
    #pragma unroll
    for (int kcl = 0; kcl < 4; ++kcl) {
        const int k0 = (half * 4 + kcl) * 32 + kbase;
        s8v af = *(const s8v*)&sA[(arow * DD + k0) ^ asw];
        s8v bf = *(const s8v*)&sB[(brow * DD + k0) ^ bsw];
        acc = __builtin_amdgcn_mfma_f32_16x16x32_bf16(af, bf, acc, 0, 0, 0);
    }
    if (half == 1) sCmb[sub * 64 + l] = acc;
    __syncthreads();

    // ---- epilogue (waves 0..3): combine halves, distances, relu terms ------
    float s = 0.f;
    if (half == 0) {
        v4f o = sCmb[sub * 64 + l];
        acc += o;
        const int jl  = wj * 16 + (l & 15);
        const int jg  = j0 + jl;
        const float nbj = sNb[jl];
        #pragma unroll
        for (int r = 0; r < 4; ++r) {
            const int il = wi * 16 + (l >> 4) * 4 + r;  // C/D: col=l&15, row=(l>>4)*4+r
            const int ig = i0 + il;
            float D2   = sNa[il] + nbj - 2.0f * acc[r];
            float dist = sqrtf(fmaxf(D2, 0.f));
            if (ig != jg) s += fmaxf(sDap[il] - dist + MARGINV, 0.f);
        }
        if (doe && t < TT) s += fmaxf(sDap[t] - sDae[t] + MARGINV, 0.f);
    }

    // ---- deterministic block reduction -> one partial ----------------------
    #pragma unroll
    for (int off = 32; off; off >>= 1) s += __shfl_down(s, off);
    if (half == 0 && l == 0) sRed[w] = s;
    __syncthreads();
    if (t == 0) partial[blockIdx.x] = ((sRed[0] + sRed[1]) + sRed[2]) + sRed[3];
}

// ---------------------------------------------------------------------------
// Final deterministic fixed-order sum of the 256 partials.
__global__ void __launch_bounds__(64) triplet_reduce_kernel(
    const float* __restrict__ partial, float* __restrict__ out)
{
    int t = threadIdx.x;
    float x0 = partial[t];
    float x1 = partial[t + 64];
    float x2 = partial[t + 128];
    float x3 = partial[t + 192];
    float x = ((x0 + x1) + x2) + x3;
    #pragma unroll
    for (int off = 32; off; off >>= 1) x += __shfl_down(x, off);
    if (t == 0) out[0] = x * INV_N;
}

extern "C" void kernel_launch(void* const* d_in, const int* in_sizes, int n_in,
                              void* d_out, int out_size, void* d_ws, size_t ws_size,
                              hipStream_t stream) {
    const float* a = (const float*)d_in[0];
    const float* b = (const float*)d_in[1];
    const float* c = (const float*)d_in[2];
    const float* d = (const float*)d_in[3];
    float* partial = (float*)d_ws;               // 256 floats

    triplet_tile_kernel<<<NBLK, 512, 0, stream>>>(a, b, c, d, partial);
    triplet_reduce_kernel<<<1, 64, 0, stream>>>(partial, (float*)d_out);
}

// Round 6
// 12.629 us; speedup vs baseline: 1.2089x; 1.0497x over previous
//
#include <hip/hip_runtime.h>

// TripletHardLoss. Round-3 structure, single isolated change: 512 blocks of
// 32(i) x 16(j) tiles -> 2 blocks/CU -> 2 waves/SIMD for latency hiding.
// Phases (as round 3): coalesced fp32->bf16 stage to swizzled LDS; fp32 norm/
// diagonal pass from L1-hit re-reads (8-lane groups); MFMA from LDS (2 subtiles
// x 2 K-halves across 4 waves, 2KB LDS combine); fp32 epilogue; deterministic
// block + final reduce.
// Math: a' = a + eps;  ||a'_i - b_j||^2 = na[i] + nb[j] - 2 (a'_i . b_j).
// Gram via bf16 MFMA (absmax 0 measured vs 2.3e-2 threshold); norms/diagonals
// exact fp32.

#define EPSV 1e-6f
#define MARGINV 1.0f

typedef float  v4f  __attribute__((ext_vector_type(4)));
typedef short  s8v  __attribute__((ext_vector_type(8)));

constexpr int BB = 512;
constexpr int DD = 256;
constexpr int D4 = DD / 4;        // 64 float4 per row
constexpr int TI = 32;            // i-rows per tile
constexpr int TJ = 16;            // j-cols per tile
constexpr int NBJ = BB / TJ;      // 32
constexpr int NBLK = (BB / TI) * NBJ;   // 512 blocks
constexpr float INV_N = 1.0f / (513.0f * 512.0f);

__device__ __forceinline__ unsigned short f2bf(float f) {
    unsigned int u = __float_as_uint(f);
    unsigned int r = (u + 0x7FFFu + ((u >> 16) & 1u)) >> 16;   // RNE
    return (unsigned short)r;
}
__device__ __forceinline__ unsigned int pk(float x, float y) {
    return (unsigned int)f2bf(x) | ((unsigned int)f2bf(y) << 16);
}

__global__ void __launch_bounds__(256) triplet_tile_kernel(
    const float* __restrict__ a, const float* __restrict__ b,
    const float* __restrict__ c, const float* __restrict__ d,
    float* __restrict__ partial)
{
    __shared__ __align__(16) unsigned short sA[TI * DD];  // 16 KB bf16 a'
    __shared__ __align__(16) unsigned short sB[TJ * DD];  //  8 KB bf16 b
    __shared__ v4f   sCmb[2 * 64];                        //  2 KB K-half combine
    __shared__ float sNa[TI], sNb[TJ], sDap[TI], sDae[TI];
    __shared__ float sRed[4];

    const int t  = threadIdx.x;
    const int l  = t & 63;
    const int w  = t >> 6;                 // wave 0..3
    const int bi = blockIdx.x >> 5;        // 0..15
    const int bj = blockIdx.x & (NBJ - 1); // 0..31
    const int i0 = bi * TI;
    const int j0 = bj * TJ;

    const float4* a4 = (const float4*)a;
    const float4* b4 = (const float4*)b;
    const bool doe = (bj == 1) || (bj == 2);
    const float4* e4 = (const float4*)((bj == 1) ? c : d);

    // ---- stage: 48 rows (32 A + 16 B) x 64 float4; 12 f4/thread, coalesced -
    #pragma unroll
    for (int kk = 0; kk < 12; ++kk) {
        const int idx  = t + kk * 256;
        const int row  = idx >> 6;         // 0..47
        const int col4 = idx & 63;
        if (row < TI) {
            float4 av = a4[(i0 + row) * D4 + col4];
            av.x += EPSV; av.y += EPSV; av.z += EPSV; av.w += EPSV;
            const int sw = (row & 7) << 3;
            *(uint2*)&sA[(row * DD + col4 * 4) ^ sw] =
                make_uint2(pk(av.x, av.y), pk(av.z, av.w));
        } else {
            const int br = row - TI;       // 0..15
            float4 bv = b4[(j0 + br) * D4 + col4];
            const int sw = (br & 7) << 3;
            *(uint2*)&sB[(br * DD + col4 * 4) ^ sw] =
                make_uint2(pk(bv.x, bv.y), pk(bv.z, bv.w));
        }
    }

    // ---- norm/diag pass: 8-lane groups, L1-hit re-reads (round-3 pattern) --
    {
        const int row = t >> 3, seg = t & 7;     // row 0..31
        float na = 0.f, dap = 0.f;
        #pragma unroll
        for (int q = 0; q < 8; ++q) {
            const int c4 = seg + q * 8;
            float4 av = a4[(i0 + row) * D4 + c4];
            av.x += EPSV; av.y += EPSV; av.z += EPSV; av.w += EPSV;
            float4 biv = b4[(i0 + row) * D4 + c4];
            na += av.x * av.x + av.y * av.y + av.z * av.z + av.w * av.w;
            float e0 = av.x - biv.x, e1 = av.y - biv.y;
            float e2 = av.z - biv.z, e3 = av.w - biv.w;
            dap += e0 * e0 + e1 * e1 + e2 * e2 + e3 * e3;
        }
        #pragma unroll
        for (int off = 4; off; off >>= 1) {
            na  += __shfl_down(na,  off, 8);
            dap += __shfl_down(dap, off, 8);
        }
        if (seg == 0) { sNa[row] = na; sDap[row] = sqrtf(dap); }

        if (row < TJ) {                          // nb for the 16 b-tile rows
            float nb = 0.f;
            #pragma unroll
            for (int q = 0; q < 8; ++q) {
                const int c4 = seg + q * 8;
                float4 bv = b4[(j0 + row) * D4 + c4];
                nb += bv.x * bv.x + bv.y * bv.y + bv.z * bv.z + bv.w * bv.w;
            }
            #pragma unroll
            for (int off = 4; off; off >>= 1) nb += __shfl_down(nb, off, 8);
            if (seg == 0) sNb[row] = nb;
        }

        if (doe) {                               // c (bj==1) / d (bj==2) diag
            float dae = 0.f;
            #pragma unroll
            for (int q = 0; q < 8; ++q) {
                const int c4 = seg + q * 8;
                float4 av = a4[(i0 + row) * D4 + c4];
                av.x += EPSV; av.y += EPSV; av.z += EPSV; av.w += EPSV;
                float4 ev = e4[(i0 + row) * D4 + c4];
                float f0 = av.x - ev.x, f1 = av.y - ev.y;
                float f2 = av.z - ev.z, f3 = av.w - ev.w;
                dae += f0 * f0 + f1 * f1 + f2 * f2 + f3 * f3;
            }
            #pragma unroll
            for (int off = 4; off; off >>= 1) dae += __shfl_down(dae, off, 8);
            if (seg == 0) sDae[row] = sqrtf(dae);
        }
    }
    __syncthreads();

    // ---- MFMA: 2 subtiles (16x16) x 2 K-halves across 4 waves --------------
    const int sub   = w & 1;                // i half of the 32 rows
    const int half  = w >> 1;               // K half
    const int arow  = sub * 16 + (l & 15);
    const int brow  = l & 15;
    const int asw   = (arow & 7) << 3;
    const int bsw   = (brow & 7) << 3;
    const int kbase = (l >> 4) * 8;

    v4f acc = {0.f, 0.f, 0.f, 0.f};
    #pragma unroll
    for (int kcl = 0; kcl < 4; ++kcl) {
        const int k0 = (half * 4 + kcl) * 32 + kbase;
        s8v af = *(const s8v*)&sA[(arow * DD + k0) ^ asw];
        s8v bf = *(const s8v*)&sB[(brow * DD + k0) ^ bsw];
        acc = __builtin_amdgcn_mfma_f32_16x16x32_bf16(af, bf, acc, 0, 0, 0);
    }
    if (half == 1) sCmb[sub * 64 + l] = acc;
    __syncthreads();

    // ---- epilogue (waves 0..1): combine halves, distances, relu ------------
    float s = 0.f;
    if (half == 0) {
        acc += sCmb[sub * 64 + l];
        const int jl  = l & 15;             // C/D: col = l&15
        const int jg  = j0 + jl;
        const float nbj = sNb[jl];
        #pragma unroll
        for (int r = 0; r < 4; ++r) {
            const int il = sub * 16 + (l >> 4) * 4 + r;  // row = (l>>4)*4 + r
            const int ig = i0 + il;
            float D2   = sNa[il] + nbj - 2.0f * acc[r];
            float dist = sqrtf(fmaxf(D2, 0.f));
            if (ig != jg) s += fmaxf(sDap[il] - dist + MARGINV, 0.f);
        }
        if (doe && t < TI) s += fmaxf(sDap[t] - sDae[t] + MARGINV, 0.f);
    }

    // ---- deterministic block reduction -> one partial ----------------------
    #pragma unroll
    for (int off = 32; off; off >>= 1) s += __shfl_down(s, off);
    if (l == 0) sRed[w] = s;
    __syncthreads();
    if (t == 0) partial[blockIdx.x] = ((sRed[0] + sRed[1]) + sRed[2]) + sRed[3];
}

// ---------------------------------------------------------------------------
// Final deterministic fixed-order sum of the 512 partials.
__global__ void __launch_bounds__(64) triplet_reduce_kernel(
    const float* __restrict__ partial, float* __restrict__ out)
{
    const int t = threadIdx.x;
    float x = 0.f;
    #pragma unroll
    for (int q = 0; q < 8; ++q) x += partial[t + q * 64];
    #pragma unroll
    for (int off = 32; off; off >>= 1) x += __shfl_down(x, off);
    if (t == 0) out[0] = x * INV_N;
}

extern "C" void kernel_launch(void* const* d_in, const int* in_sizes, int n_in,
                              void* d_out, int out_size, void* d_ws, size_t ws_size,
                              hipStream_t stream) {
    const float* a = (const float*)d_in[0];
    const float* b = (const float*)d_in[1];
    const float* c = (const float*)d_in[2];
    const float* d = (const float*)d_in[3];
    float* partial = (float*)d_ws;               // 512 floats

    triplet_tile_kernel<<<NBLK, 256, 0, stream>>>(a, b, c, d, partial);
    triplet_reduce_kernel<<<1, 64, 0, stream>>>(partial, (float*)d_out);
}